// Round 23
// baseline (111.528 us; speedup 1.0000x reference)
//
#include <hip/hip_runtime.h>
#include <hip/hip_bf16.h>

typedef __attribute__((ext_vector_type(8))) short bf16x8;
typedef __attribute__((ext_vector_type(4))) float f32x4;
typedef __attribute__((ext_vector_type(4))) unsigned u32x4;

typedef __attribute__((address_space(1))) const void gv_t;
typedef __attribute__((address_space(3))) void lv_t;

static __device__ __forceinline__ void gload16(const void* g, void* l) {
    __builtin_amdgcn_global_load_lds((gv_t*)g, (lv_t*)l, 16, 0, 0);
}

static __device__ __forceinline__ f32x4 mfma16(bf16x8 a, bf16x8 b, f32x4 c) {
    return __builtin_amdgcn_mfma_f32_16x16x32_bf16(a, b, c, 0, 0, 0);
}

// hardware bf16 convert, RNE
static __device__ __forceinline__ unsigned short f2bf(float x) {
    __bf16 b = (__bf16)x;
    return __builtin_bit_cast(unsigned short, b);
}
static __device__ __forceinline__ unsigned pk2(float lo, float hi) {
    return (unsigned)f2bf(lo) | ((unsigned)f2bf(hi) << 16);
}

// ---- problem sizes (fixed) ----
#define NN 1024   // HID / E_F
#define KK 1024   // E_PHI / HID
#define BK 32
#define NKT (KK / BK)
#define AP 72       // padded LDS row stride for attention K/V tiles.
                    // NOTE: AP=76 measured ZERO bank conflicts but +1.5us (R21) —
                    // conflicts are off the critical path; 72 is the measured optimum.
// Q pre-scaled by 0.125*log2(e) in the projection; softmax = exp2(s - SOFF2), exact.
#define SOFF2 17.3123404907f   // 12 * log2(e)

// ============ fused prep: fp32->bf16 convert (q,k,v) + weight transpose ============
__global__ void prep_k(const float* __restrict__ q, const float* __restrict__ k,
                       const float* __restrict__ v, unsigned short* __restrict__ qkvb,
                       const float* __restrict__ w0, const float* __restrict__ w1,
                       const float* __restrict__ w2, const float* __restrict__ w3,
                       unsigned short* __restrict__ Wt)
{
    __shared__ float t[32][33];
    const int id = blockIdx.x;
    if (id < 6144) {
        const int z = id >> 11;
        const int xb = id & 2047;
        const float* src = (z == 0) ? q : (z == 1) ? k : v;
        unsigned short* d = qkvb + (size_t)z * 4194304u;
        const size_t i = ((size_t)xb * 256 + threadIdx.x) * 8;
        float4 a = *reinterpret_cast<const float4*>(&src[i]);
        float4 b = *reinterpret_cast<const float4*>(&src[i + 4]);
        bf16x8 o;
        o[0] = (short)f2bf(a.x); o[1] = (short)f2bf(a.y);
        o[2] = (short)f2bf(a.z); o[3] = (short)f2bf(a.w);
        o[4] = (short)f2bf(b.x); o[5] = (short)f2bf(b.y);
        o[6] = (short)f2bf(b.z); o[7] = (short)f2bf(b.w);
        *reinterpret_cast<bf16x8*>(&d[i]) = o;
    } else {
        const int tt2 = id - 6144;
        const int z  = tt2 >> 10;
        const int bx = tt2 & 31, by = (tt2 >> 5) & 31;
        const float* W = (z == 0) ? w0 : (z == 1) ? w1 : (z == 2) ? w2 : w3;
        unsigned short* D = Wt + (size_t)z * 1048576u;
        const int tx = threadIdx.x & 31, ty = threadIdx.x >> 5;   // (32,8)
        const int x  = bx * 32 + tx;            // n
        const int y0 = by * 32;                 // k base
        for (int i = ty; i < 32; i += 8) t[i][tx] = W[(size_t)(y0 + i) * 1024 + x];
        __syncthreads();
        const int xo = y0 + tx;                  // k
        for (int i = ty; i < 32; i += 8)
            D[(size_t)(bx * 32 + i) * 1024 + xo] = f2bf(t[tx][i]);  // D[n][k] = W[k][n]
    }
}

// ============ bf16 MFMA GEMM (proj), counted-vmcnt 3-buffer pipeline ============
__global__ __launch_bounds__(256, 3)
void gemm_proj_k(const unsigned short* __restrict__ Abase,
                 const unsigned short* __restrict__ Btbase,
                 unsigned short* __restrict__ Cbase,
                 unsigned short* __restrict__ C2,
                 const float* __restrict__ bias)
{
    __shared__ unsigned short As[3][4096];
    __shared__ unsigned short Bs[3][4096];

    const int f   = blockIdx.x;
    const int xcd = f & 7;
    const int g   = f >> 3;
    const int z   = g >> 5;
    const int rr  = g & 31;
    const int bx  = xcd * 4 + (rr & 3);
    const int by  = rr >> 2;

    const unsigned short* A  = Abase  + (size_t)z * 4194304u;
    const unsigned short* Bt = Btbase + (size_t)z * 1048576u;

    const int tid = threadIdx.x;
    const int wid = tid >> 6, lane = tid & 63;
    const int lg = lane >> 4, lc = lane & 15;
    const int brow = bx * 128;
    const int bcol = by * 128;
    const int wr = (wid >> 1) * 64;
    const int wc = (wid & 1) * 64;

    const int srow = tid >> 2;
    const int scol = (tid & 3) * 8;

    f32x4 acc[4][4];
#pragma unroll
    for (int i = 0; i < 4; ++i)
#pragma unroll
        for (int j = 0; j < 4; ++j) acc[i][j] = (f32x4){0.f, 0.f, 0.f, 0.f};

    auto issue_tile = [&](int kt, int c) {
        const int k0 = kt * BK;
        gload16(&A [(size_t)(brow + srow)      * KK + k0 + scol], &As[c][tid * 8]);
        gload16(&A [(size_t)(brow + 64 + srow) * KK + k0 + scol], &As[c][2048 + tid * 8]);
        gload16(&Bt[(size_t)(bcol + srow)      * KK + k0 + scol], &Bs[c][tid * 8]);
        gload16(&Bt[(size_t)(bcol + 64 + srow) * KK + k0 + scol], &Bs[c][2048 + tid * 8]);
    };
    auto compute_tile = [&](int c) {
        bf16x8 af[4], bfr[4];
#pragma unroll
        for (int i = 0; i < 4; ++i)
            af[i] = *reinterpret_cast<const bf16x8*>(&As[c][(wr + i * 16 + lc) * 32 + lg * 8]);
#pragma unroll
        for (int j = 0; j < 4; ++j)
            bfr[j] = *reinterpret_cast<const bf16x8*>(&Bs[c][(wc + j * 16 + lc) * 32 + lg * 8]);
#pragma unroll
        for (int i = 0; i < 4; ++i)
#pragma unroll
            for (int j = 0; j < 4; ++j)
                acc[i][j] = mfma16(af[i], bfr[j], acc[i][j]);
    };

    issue_tile(0, 0);
    issue_tile(1, 1);

    int c0 = 0, c1 = 1, c2 = 2;
    for (int kt = 0; kt < NKT - 1; ++kt) {
        asm volatile("s_waitcnt vmcnt(4)" ::: "memory");
        __builtin_amdgcn_s_barrier();
        __builtin_amdgcn_sched_barrier(0);
        if (kt + 2 < NKT) issue_tile(kt + 2, c2);
        compute_tile(c0);
        const int t = c0; c0 = c1; c1 = c2; c2 = t;
    }
    asm volatile("s_waitcnt vmcnt(0)" ::: "memory");
    __builtin_amdgcn_s_barrier();
    __builtin_amdgcn_sched_barrier(0);
    compute_tile(c0);

    const float scale = (z == 0) ? 0.18033688f : 1.0f;

    if (z == 2) {
#pragma unroll
        for (int j = 0; j < 4; ++j) {
            const int col = bcol + wc + j * 16 + lc;   // hid index
            const int h = col >> 6, d = col & 63;
            const float bb = bias[col];
#pragma unroll
            for (int i = 0; i < 4; ++i) {
                const int row0 = brow + wr + i * 16 + lg * 4;   // token index
                const int b = row0 >> 11, s0 = row0 & 2047;
                const size_t o = ((size_t)((b * 16 + h) * 64 + d)) * 2048u + s0;
                uint2 st;
                st.x = pk2(acc[i][j][0] + bb, acc[i][j][1] + bb);
                st.y = pk2(acc[i][j][2] + bb, acc[i][j][3] + bb);
                *reinterpret_cast<uint2*>(&C2[o]) = st;
            }
        }
    } else {
#pragma unroll
        for (int j = 0; j < 4; ++j) {
            const int col = bcol + wc + j * 16 + lc;
#pragma unroll
            for (int i = 0; i < 4; ++i) {
                const int row0 = brow + wr + i * 16 + lg * 4;
#pragma unroll
                for (int r = 0; r < 4; ++r)
                    Cbase[(size_t)z * 4194304u + (size_t)(row0 + r) * NN + col] =
                        f2bf(acc[i][j][r] * scale);
            }
        }
    }
}

// ============ out GEMM: TM=64, TN=128, BK=32, 3-buffer vmcnt(3) (proven) ============
__global__ __launch_bounds__(256, 2)
void gemm_out_k(const unsigned short* __restrict__ A,
                const unsigned short* __restrict__ Bt,
                float* __restrict__ C,
                const float* __restrict__ bias)
{
    __shared__ unsigned short As[3][2048];    // 64 x 32
    __shared__ unsigned short Bs[3][4096];    // 128 x 32

    const int f = blockIdx.x, xcd = f & 7, g = f >> 3;
    const int bx = xcd * 8 + (g & 7);          // 64 row panels of 64
    const int by = g >> 3;                     // 8 col panels of 128
    const int tid = threadIdx.x;
    const int wid = tid >> 6, lane = tid & 63;
    const int lg = lane >> 4, lc = lane & 15;
    const int brow = bx * 64, bcol = by * 128;
    const int wc = wid * 32;                   // 4 waves x 32 cols

    const int srow = tid >> 2;                 // 0..63
    const int scol = (tid & 3) * 8;            // 0..24

    f32x4 acc[4][2];
#pragma unroll
    for (int i = 0; i < 4; ++i)
#pragma unroll
        for (int j = 0; j < 2; ++j) acc[i][j] = (f32x4){0.f, 0.f, 0.f, 0.f};

    auto issue_tile = [&](int kt, int c) {
        const int k0 = kt * BK;
        gload16(&A [(size_t)(brow + srow)      * KK + k0 + scol], &As[c][tid * 8]);
        gload16(&Bt[(size_t)(bcol + srow)      * KK + k0 + scol], &Bs[c][tid * 8]);
        gload16(&Bt[(size_t)(bcol + 64 + srow) * KK + k0 + scol], &Bs[c][2048 + tid * 8]);
    };
    auto compute_tile = [&](int c) {
        bf16x8 af[4], bfr[2];
#pragma unroll
        for (int i = 0; i < 4; ++i)
            af[i] = *reinterpret_cast<const bf16x8*>(&As[c][(i * 16 + lc) * 32 + lg * 8]);
#pragma unroll
        for (int j = 0; j < 2; ++j)
            bfr[j] = *reinterpret_cast<const bf16x8*>(&Bs[c][(wc + j * 16 + lc) * 32 + lg * 8]);
#pragma unroll
        for (int i = 0; i < 4; ++i)
#pragma unroll
            for (int j = 0; j < 2; ++j)
                acc[i][j] = mfma16(af[i], bfr[j], acc[i][j]);
    };

    issue_tile(0, 0);
    issue_tile(1, 1);

    int c0 = 0, c1 = 1, c2 = 2;
    for (int kt = 0; kt < NKT - 1; ++kt) {
        asm volatile("s_waitcnt vmcnt(3)" ::: "memory");
        __builtin_amdgcn_s_barrier();
        __builtin_amdgcn_sched_barrier(0);
        if (kt + 2 < NKT) issue_tile(kt + 2, c2);
        compute_tile(c0);
        const int t = c0; c0 = c1; c1 = c2; c2 = t;
    }
    asm volatile("s_waitcnt vmcnt(0)" ::: "memory");
    __builtin_amdgcn_s_barrier();
    __builtin_amdgcn_sched_barrier(0);
    compute_tile(c0);

#pragma unroll
    for (int j = 0; j < 2; ++j) {
        const int col = bcol + wc + j * 16 + lc;
        const float bb = bias[col];
#pragma unroll
        for (int i = 0; i < 4; ++i) {
            const int row0 = brow + i * 16 + lg * 4;
#pragma unroll
            for (int r = 0; r < 4; ++r)
                C[(size_t)(row0 + r) * NN + col] = acc[i][j][r] + bb;
        }
    }
}

// ============ flash attention: swapped QK^T + PERMUTED-K staging ============
// R13 structure; R23 change: next-tile REGISTER loads issued BEFORE lgkmcnt+barrier
// (loads target regs not LDS -> no cross-wave race; T14 issue-early, hides HBM/L2
// latency under the barrier drain + QK fragment reads).
__global__ __launch_bounds__(256, 4)
void attn_k(const unsigned short* __restrict__ qh,
            const unsigned short* __restrict__ kh,
            const unsigned short* __restrict__ vt,
            unsigned short* __restrict__ out)
{
    __shared__ unsigned short Ks[2][64 * AP];    // row = permuted key slot, col = d
    __shared__ unsigned short Vs[2][64 * AP];    // row = d idx, col = key (linear)

    const int id = blockIdx.x;                     // 0..1023
    const int u  = id >> 5;                        // 0..31
    const int qt = (u < 16) ? u : 47 - u;          // ids at distance 512 complementary
    const int bh = (id & 7) * 4 + ((id >> 3) & 3);
    const int b = bh >> 4, h = bh & 15;
    const int tid = threadIdx.x, wid = tid >> 6, lane = tid & 63;
    const int lg = lane >> 4, lc = lane & 15;
    const int q0w = qt * 64 + wid * 16;            // wave's first q row

    const size_t base = (size_t)b * 2048u * 1024u + (size_t)h * 64u;
    const unsigned short* Qb  = qh + base;
    const unsigned short* Kb  = kh + base;
    const unsigned short* Vtb = vt + (size_t)bh * 131072u;   // 64*2048

    const int r0 = tid >> 3, kof = (tid & 7) * 8;
    // permuted key for staging row r0 (r0 in 0..31); row r0+32 holds kperm+32
    const int kperm = ((r0 & 12) << 1) | ((r0 >> 2) & 4) | (r0 & 3);

    bf16x8 qf[2];
#pragma unroll
    for (int s = 0; s < 2; ++s)
        qf[s] = *reinterpret_cast<const bf16x8*>(&Qb[(size_t)(q0w + lc) * 1024 + s * 32 + lg * 8]);

    f32x4 accT[4];   // accT[di][r] = O[q=lc][d = di*16 + 4*lg + r]
#pragma unroll
    for (int d = 0; d < 4; ++d) accT[d] = (f32x4){0.f, 0.f, 0.f, 0.f};
    float lsum = 0.f;

    // prologue: tile 0 into regs (K rows permuted)
    bf16x8 ka0 = *reinterpret_cast<const bf16x8*>(&Kb [(size_t)(kperm)      * 1024 + kof]);
    bf16x8 ka1 = *reinterpret_cast<const bf16x8*>(&Kb [(size_t)(32 + kperm) * 1024 + kof]);
    bf16x8 va0 = *reinterpret_cast<const bf16x8*>(&Vtb[(size_t)(r0)      * 2048 + kof]);
    bf16x8 va1 = *reinterpret_cast<const bf16x8*>(&Vtb[(size_t)(32 + r0) * 2048 + kof]);

    for (int kt = 0; kt <= qt; ++kt) {
        const int cur = kt & 1;
        const int k0 = kt * 64;

        // stage tile kt into buf[cur]
        *reinterpret_cast<bf16x8*>(&Ks[cur][(r0)      * AP + kof]) = ka0;
        *reinterpret_cast<bf16x8*>(&Ks[cur][(32 + r0) * AP + kof]) = ka1;
        *reinterpret_cast<bf16x8*>(&Vs[cur][(r0)      * AP + kof]) = va0;
        *reinterpret_cast<bf16x8*>(&Vs[cur][(32 + r0) * AP + kof]) = va1;

        // issue NEXT tile's register loads BEFORE the barrier: they drain during the
        // barrier + QK fragment reads (regs, not LDS -> no cross-wave hazard; the
        // ds_writes above consume the old values first by program order).
        if (kt < qt) {
            const int kn = k0 + 64;
            ka0 = *reinterpret_cast<const bf16x8*>(&Kb [(size_t)(kn + kperm)      * 1024 + kof]);
            ka1 = *reinterpret_cast<const bf16x8*>(&Kb [(size_t)(kn + 32 + kperm) * 1024 + kof]);
            va0 = *reinterpret_cast<const bf16x8*>(&Vtb[(size_t)(r0)      * 2048 + kn + kof]);
            va1 = *reinterpret_cast<const bf16x8*>(&Vtb[(size_t)(32 + r0) * 2048 + kn + kof]);
        }

        asm volatile("s_waitcnt lgkmcnt(0)" ::: "memory");
        __builtin_amdgcn_s_barrier();
        __builtin_amdgcn_sched_barrier(0);

        // swapped QK^T: sc[g][r] = S[key = k0+Key(16g+4lg+r)][q = q0w+lc]
        f32x4 sc[4];
#pragma unroll
        for (int g = 0; g < 4; ++g) sc[g] = (f32x4){0.f, 0.f, 0.f, 0.f};
        __builtin_amdgcn_s_setprio(1);
#pragma unroll
        for (int s = 0; s < 2; ++s)
#pragma unroll
            for (int g = 0; g < 4; ++g) {
                bf16x8 kf = *reinterpret_cast<const bf16x8*>(
                    &Ks[cur][(g * 16 + lc) * AP + s * 32 + lg * 8]);
                sc[g] = mfma16(kf, qf[s], sc[g]);
            }
        __builtin_amdgcn_s_setprio(0);

        if (kt == qt) {   // diagonal tile: strict causal + (0,0), permuted key ids
            const int qi = q0w + lc;
#pragma unroll
            for (int g = 0; g < 4; ++g)
#pragma unroll
                for (int r = 0; r < 4; ++r) {
                    const int ki = k0 + ((g & 2) << 4) + 8 * lg + 4 * (g & 1) + r;
                    const bool keep = (ki < qi) || (qi == 0 && ki == 0);
                    if (!keep) sc[g][r] = -1e30f;
                }
        }

        // fixed-shift softmax, fully lane-local
        float p[4][4];
#pragma unroll
        for (int g = 0; g < 4; ++g)
#pragma unroll
            for (int r = 0; r < 4; ++r) {
                p[g][r] = exp2f(sc[g][r] - SOFF2);
                lsum += p[g][r];
            }

        // PV: B-frag is lane-local by construction (permuted K staging)
#pragma unroll
        for (int s = 0; s < 2; ++s) {
            u32x4 fr;
            fr[0] = pk2(p[2 * s][0],     p[2 * s][1]);
            fr[1] = pk2(p[2 * s][2],     p[2 * s][3]);
            fr[2] = pk2(p[2 * s + 1][0], p[2 * s + 1][1]);
            fr[3] = pk2(p[2 * s + 1][2], p[2 * s + 1][3]);
            bf16x8 pb = __builtin_bit_cast(bf16x8, fr);
            __builtin_amdgcn_s_setprio(1);
#pragma unroll
            for (int di = 0; di < 4; ++di) {
                bf16x8 vf = *reinterpret_cast<const bf16x8*>(
                    &Vs[cur][(di * 16 + lc) * AP + s * 32 + lg * 8]);
                accT[di] = mfma16(vf, pb, accT[di]);
            }
            __builtin_amdgcn_s_setprio(0);
        }
    }

    // full row sum for q=lc: combine the 4 lg groups
    lsum += __shfl_xor(lsum, 16);
    lsum += __shfl_xor(lsum, 32);
    const float inv = 1.0f / lsum;

    const size_t orow = (size_t)(b * 2048 + q0w + lc) * 1024 + (size_t)h * 64 + lg * 4;
#pragma unroll
    for (int di = 0; di < 4; ++di) {
        unsigned lo  = pk2(accT[di][0] * inv, accT[di][1] * inv);
        unsigned hi2 = pk2(accT[di][2] * inv, accT[di][3] * inv);
        uint2 st; st.x = lo; st.y = hi2;
        *reinterpret_cast<uint2*>(&out[orow + di * 16]) = st;
    }
}

extern "C" void kernel_launch(void* const* d_in, const int* in_sizes, int n_in,
                              void* d_out, int out_size, void* d_ws, size_t ws_size,
                              hipStream_t stream)
{
    const float* q   = (const float*)d_in[0];
    const float* k   = (const float*)d_in[1];
    const float* v   = (const float*)d_in[2];
    const float* W_q = (const float*)d_in[3];
    const float* W_k = (const float*)d_in[4];
    const float* W_v = (const float*)d_in[5];
    const float* b_v = (const float*)d_in[6];
    const float* W_o = (const float*)d_in[7];
    const float* b_o = (const float*)d_in[8];

    char* w = (char*)d_ws;
    unsigned short* qkvb = (unsigned short*)w;                 // 3 x 4194304 bf16 (24 MiB)
    unsigned short* Wt   = (unsigned short*)(w + 25165824);    // 4 x 1048576 bf16 (8 MiB)
    unsigned short* ph   = (unsigned short*)(w + 33554432);    // qh,kh bf16 + vt slot (24 MiB)
    unsigned short* attn = (unsigned short*)(w + 58720256);    // 8 MiB
    unsigned short* vt   = ph + 2 * 4194304;                   // V^T written directly by proj z==2

    prep_k <<<dim3(10240, 1, 1), 256, 0, stream>>>(q, k, v, qkvb, W_q, W_k, W_v, W_o, Wt);
    gemm_proj_k<<<dim3(768, 1, 1), 256, 0, stream>>>(qkvb, Wt, ph, vt, b_v);
    attn_k <<<dim3(1024, 1, 1), 256, 0, stream>>>(ph, ph + 4194304, vt, attn);
    gemm_out_k<<<dim3(512, 1, 1), 256, 0, stream>>>(attn, Wt + 3 * 1048576, (float*)d_out, b_o);
}

// Round 24
// 110.242 us; speedup vs baseline: 1.0117x; 1.0117x over previous
//
#include <hip/hip_runtime.h>
#include <hip/hip_bf16.h>

typedef __attribute__((ext_vector_type(8))) short bf16x8;
typedef __attribute__((ext_vector_type(4))) float f32x4;
typedef __attribute__((ext_vector_type(4))) unsigned u32x4;

typedef __attribute__((address_space(1))) const void gv_t;
typedef __attribute__((address_space(3))) void lv_t;

static __device__ __forceinline__ void gload16(const void* g, void* l) {
    __builtin_amdgcn_global_load_lds((gv_t*)g, (lv_t*)l, 16, 0, 0);
}

static __device__ __forceinline__ f32x4 mfma16(bf16x8 a, bf16x8 b, f32x4 c) {
    return __builtin_amdgcn_mfma_f32_16x16x32_bf16(a, b, c, 0, 0, 0);
}

// hardware bf16 convert, RNE
static __device__ __forceinline__ unsigned short f2bf(float x) {
    __bf16 b = (__bf16)x;
    return __builtin_bit_cast(unsigned short, b);
}
static __device__ __forceinline__ unsigned pk2(float lo, float hi) {
    return (unsigned)f2bf(lo) | ((unsigned)f2bf(hi) << 16);
}

// ---- problem sizes (fixed) ----
#define NN 1024   // HID / E_F
#define KK 1024   // E_PHI / HID
#define BK 32
#define NKT (KK / BK)
#define AP 72       // padded LDS row stride for attention K/V tiles.
                    // NOTE: AP=76 measured ZERO bank conflicts but +1.5us (R21) —
                    // conflicts are off the critical path; 72 is the measured optimum.
// Q pre-scaled by 0.125*log2(e) in the projection; softmax = exp2(s - SOFF2), exact.
#define SOFF2 17.3123404907f   // 12 * log2(e)

// ============ fused prep: fp32->bf16 convert (q,k,v) + weight transpose ============
__global__ void prep_k(const float* __restrict__ q, const float* __restrict__ k,
                       const float* __restrict__ v, unsigned short* __restrict__ qkvb,
                       const float* __restrict__ w0, const float* __restrict__ w1,
                       const float* __restrict__ w2, const float* __restrict__ w3,
                       unsigned short* __restrict__ Wt)
{
    __shared__ float t[32][33];
    const int id = blockIdx.x;
    if (id < 6144) {
        const int z = id >> 11;
        const int xb = id & 2047;
        const float* src = (z == 0) ? q : (z == 1) ? k : v;
        unsigned short* d = qkvb + (size_t)z * 4194304u;
        const size_t i = ((size_t)xb * 256 + threadIdx.x) * 8;
        float4 a = *reinterpret_cast<const float4*>(&src[i]);
        float4 b = *reinterpret_cast<const float4*>(&src[i + 4]);
        bf16x8 o;
        o[0] = (short)f2bf(a.x); o[1] = (short)f2bf(a.y);
        o[2] = (short)f2bf(a.z); o[3] = (short)f2bf(a.w);
        o[4] = (short)f2bf(b.x); o[5] = (short)f2bf(b.y);
        o[6] = (short)f2bf(b.z); o[7] = (short)f2bf(b.w);
        *reinterpret_cast<bf16x8*>(&d[i]) = o;
    } else {
        const int tt2 = id - 6144;
        const int z  = tt2 >> 10;
        const int bx = tt2 & 31, by = (tt2 >> 5) & 31;
        const float* W = (z == 0) ? w0 : (z == 1) ? w1 : (z == 2) ? w2 : w3;
        unsigned short* D = Wt + (size_t)z * 1048576u;
        const int tx = threadIdx.x & 31, ty = threadIdx.x >> 5;   // (32,8)
        const int x  = bx * 32 + tx;            // n
        const int y0 = by * 32;                 // k base
        for (int i = ty; i < 32; i += 8) t[i][tx] = W[(size_t)(y0 + i) * 1024 + x];
        __syncthreads();
        const int xo = y0 + tx;                  // k
        for (int i = ty; i < 32; i += 8)
            D[(size_t)(bx * 32 + i) * 1024 + xo] = f2bf(t[tx][i]);  // D[n][k] = W[k][n]
    }
}

// ============ bf16 MFMA GEMM (proj), counted-vmcnt 3-buffer pipeline ============
__global__ __launch_bounds__(256, 3)
void gemm_proj_k(const unsigned short* __restrict__ Abase,
                 const unsigned short* __restrict__ Btbase,
                 unsigned short* __restrict__ Cbase,
                 unsigned short* __restrict__ C2,
                 const float* __restrict__ bias)
{
    __shared__ unsigned short As[3][4096];
    __shared__ unsigned short Bs[3][4096];

    const int f   = blockIdx.x;
    const int xcd = f & 7;
    const int g   = f >> 3;
    const int z   = g >> 5;
    const int rr  = g & 31;
    const int bx  = xcd * 4 + (rr & 3);
    const int by  = rr >> 2;

    const unsigned short* A  = Abase  + (size_t)z * 4194304u;
    const unsigned short* Bt = Btbase + (size_t)z * 1048576u;

    const int tid = threadIdx.x;
    const int wid = tid >> 6, lane = tid & 63;
    const int lg = lane >> 4, lc = lane & 15;
    const int brow = bx * 128;
    const int bcol = by * 128;
    const int wr = (wid >> 1) * 64;
    const int wc = (wid & 1) * 64;

    const int srow = tid >> 2;
    const int scol = (tid & 3) * 8;

    f32x4 acc[4][4];
#pragma unroll
    for (int i = 0; i < 4; ++i)
#pragma unroll
        for (int j = 0; j < 4; ++j) acc[i][j] = (f32x4){0.f, 0.f, 0.f, 0.f};

    auto issue_tile = [&](int kt, int c) {
        const int k0 = kt * BK;
        gload16(&A [(size_t)(brow + srow)      * KK + k0 + scol], &As[c][tid * 8]);
        gload16(&A [(size_t)(brow + 64 + srow) * KK + k0 + scol], &As[c][2048 + tid * 8]);
        gload16(&Bt[(size_t)(bcol + srow)      * KK + k0 + scol], &Bs[c][tid * 8]);
        gload16(&Bt[(size_t)(bcol + 64 + srow) * KK + k0 + scol], &Bs[c][2048 + tid * 8]);
    };
    auto compute_tile = [&](int c) {
        bf16x8 af[4], bfr[4];
#pragma unroll
        for (int i = 0; i < 4; ++i)
            af[i] = *reinterpret_cast<const bf16x8*>(&As[c][(wr + i * 16 + lc) * 32 + lg * 8]);
#pragma unroll
        for (int j = 0; j < 4; ++j)
            bfr[j] = *reinterpret_cast<const bf16x8*>(&Bs[c][(wc + j * 16 + lc) * 32 + lg * 8]);
#pragma unroll
        for (int i = 0; i < 4; ++i)
#pragma unroll
            for (int j = 0; j < 4; ++j)
                acc[i][j] = mfma16(af[i], bfr[j], acc[i][j]);
    };

    issue_tile(0, 0);
    issue_tile(1, 1);

    int c0 = 0, c1 = 1, c2 = 2;
    for (int kt = 0; kt < NKT - 1; ++kt) {
        asm volatile("s_waitcnt vmcnt(4)" ::: "memory");
        __builtin_amdgcn_s_barrier();
        __builtin_amdgcn_sched_barrier(0);
        if (kt + 2 < NKT) issue_tile(kt + 2, c2);
        compute_tile(c0);
        const int t = c0; c0 = c1; c1 = c2; c2 = t;
    }
    asm volatile("s_waitcnt vmcnt(0)" ::: "memory");
    __builtin_amdgcn_s_barrier();
    __builtin_amdgcn_sched_barrier(0);
    compute_tile(c0);

    const float scale = (z == 0) ? 0.18033688f : 1.0f;

    if (z == 2) {
#pragma unroll
        for (int j = 0; j < 4; ++j) {
            const int col = bcol + wc + j * 16 + lc;   // hid index
            const int h = col >> 6, d = col & 63;
            const float bb = bias[col];
#pragma unroll
            for (int i = 0; i < 4; ++i) {
                const int row0 = brow + wr + i * 16 + lg * 4;   // token index
                const int b = row0 >> 11, s0 = row0 & 2047;
                const size_t o = ((size_t)((b * 16 + h) * 64 + d)) * 2048u + s0;
                uint2 st;
                st.x = pk2(acc[i][j][0] + bb, acc[i][j][1] + bb);
                st.y = pk2(acc[i][j][2] + bb, acc[i][j][3] + bb);
                *reinterpret_cast<uint2*>(&C2[o]) = st;
            }
        }
    } else {
#pragma unroll
        for (int j = 0; j < 4; ++j) {
            const int col = bcol + wc + j * 16 + lc;
#pragma unroll
            for (int i = 0; i < 4; ++i) {
                const int row0 = brow + wr + i * 16 + lg * 4;
#pragma unroll
                for (int r = 0; r < 4; ++r)
                    Cbase[(size_t)z * 4194304u + (size_t)(row0 + r) * NN + col] =
                        f2bf(acc[i][j][r] * scale);
            }
        }
    }
}

// ============ out GEMM: TM=64, TN=128, BK=32, 3-buffer vmcnt(3) (proven) ============
__global__ __launch_bounds__(256, 2)
void gemm_out_k(const unsigned short* __restrict__ A,
                const unsigned short* __restrict__ Bt,
                float* __restrict__ C,
                const float* __restrict__ bias)
{
    __shared__ unsigned short As[3][2048];    // 64 x 32
    __shared__ unsigned short Bs[3][4096];    // 128 x 32

    const int f = blockIdx.x, xcd = f & 7, g = f >> 3;
    const int bx = xcd * 8 + (g & 7);          // 64 row panels of 64
    const int by = g >> 3;                     // 8 col panels of 128
    const int tid = threadIdx.x;
    const int wid = tid >> 6, lane = tid & 63;
    const int lg = lane >> 4, lc = lane & 15;
    const int brow = bx * 64, bcol = by * 128;
    const int wc = wid * 32;                   // 4 waves x 32 cols

    const int srow = tid >> 2;                 // 0..63
    const int scol = (tid & 3) * 8;            // 0..24

    f32x4 acc[4][2];
#pragma unroll
    for (int i = 0; i < 4; ++i)
#pragma unroll
        for (int j = 0; j < 2; ++j) acc[i][j] = (f32x4){0.f, 0.f, 0.f, 0.f};

    auto issue_tile = [&](int kt, int c) {
        const int k0 = kt * BK;
        gload16(&A [(size_t)(brow + srow)      * KK + k0 + scol], &As[c][tid * 8]);
        gload16(&Bt[(size_t)(bcol + srow)      * KK + k0 + scol], &Bs[c][tid * 8]);
        gload16(&Bt[(size_t)(bcol + 64 + srow) * KK + k0 + scol], &Bs[c][2048 + tid * 8]);
    };
    auto compute_tile = [&](int c) {
        bf16x8 af[4], bfr[2];
#pragma unroll
        for (int i = 0; i < 4; ++i)
            af[i] = *reinterpret_cast<const bf16x8*>(&As[c][(i * 16 + lc) * 32 + lg * 8]);
#pragma unroll
        for (int j = 0; j < 2; ++j)
            bfr[j] = *reinterpret_cast<const bf16x8*>(&Bs[c][(wc + j * 16 + lc) * 32 + lg * 8]);
#pragma unroll
        for (int i = 0; i < 4; ++i)
#pragma unroll
            for (int j = 0; j < 2; ++j)
                acc[i][j] = mfma16(af[i], bfr[j], acc[i][j]);
    };

    issue_tile(0, 0);
    issue_tile(1, 1);

    int c0 = 0, c1 = 1, c2 = 2;
    for (int kt = 0; kt < NKT - 1; ++kt) {
        asm volatile("s_waitcnt vmcnt(3)" ::: "memory");
        __builtin_amdgcn_s_barrier();
        __builtin_amdgcn_sched_barrier(0);
        if (kt + 2 < NKT) issue_tile(kt + 2, c2);
        compute_tile(c0);
        const int t = c0; c0 = c1; c1 = c2; c2 = t;
    }
    asm volatile("s_waitcnt vmcnt(0)" ::: "memory");
    __builtin_amdgcn_s_barrier();
    __builtin_amdgcn_sched_barrier(0);
    compute_tile(c0);

#pragma unroll
    for (int j = 0; j < 2; ++j) {
        const int col = bcol + wc + j * 16 + lc;
        const float bb = bias[col];
#pragma unroll
        for (int i = 0; i < 4; ++i) {
            const int row0 = brow + i * 16 + lg * 4;
#pragma unroll
            for (int r = 0; r < 4; ++r)
                C[(size_t)(row0 + r) * NN + col] = acc[i][j][r] + bb;
        }
    }
}

// ============ flash attention: swapped QK^T + PERMUTED-K staging (R13, proven) ======
__global__ __launch_bounds__(256, 4)
void attn_k(const unsigned short* __restrict__ qh,
            const unsigned short* __restrict__ kh,
            const unsigned short* __restrict__ vt,
            unsigned short* __restrict__ out)
{
    __shared__ unsigned short Ks[2][64 * AP];    // row = permuted key slot, col = d
    __shared__ unsigned short Vs[2][64 * AP];    // row = d idx, col = key (linear)

    const int id = blockIdx.x;                     // 0..1023
    const int u  = id >> 5;                        // 0..31
    const int qt = (u < 16) ? u : 47 - u;          // ids at distance 512 complementary
    const int bh = (id & 7) * 4 + ((id >> 3) & 3);
    const int b = bh >> 4, h = bh & 15;
    const int tid = threadIdx.x, wid = tid >> 6, lane = tid & 63;
    const int lg = lane >> 4, lc = lane & 15;
    const int q0w = qt * 64 + wid * 16;            // wave's first q row

    const size_t base = (size_t)b * 2048u * 1024u + (size_t)h * 64u;
    const unsigned short* Qb  = qh + base;
    const unsigned short* Kb  = kh + base;
    const unsigned short* Vtb = vt + (size_t)bh * 131072u;   // 64*2048

    const int r0 = tid >> 3, kof = (tid & 7) * 8;
    // permuted key for staging row r0 (r0 in 0..31); row r0+32 holds kperm+32
    const int kperm = ((r0 & 12) << 1) | ((r0 >> 2) & 4) | (r0 & 3);

    bf16x8 qf[2];
#pragma unroll
    for (int s = 0; s < 2; ++s)
        qf[s] = *reinterpret_cast<const bf16x8*>(&Qb[(size_t)(q0w + lc) * 1024 + s * 32 + lg * 8]);

    f32x4 accT[4];   // accT[di][r] = O[q=lc][d = di*16 + 4*lg + r]
#pragma unroll
    for (int d = 0; d < 4; ++d) accT[d] = (f32x4){0.f, 0.f, 0.f, 0.f};
    float lsum = 0.f;

    // prologue: tile 0 into regs (K rows permuted)
    bf16x8 ka0 = *reinterpret_cast<const bf16x8*>(&Kb [(size_t)(kperm)      * 1024 + kof]);
    bf16x8 ka1 = *reinterpret_cast<const bf16x8*>(&Kb [(size_t)(32 + kperm) * 1024 + kof]);
    bf16x8 va0 = *reinterpret_cast<const bf16x8*>(&Vtb[(size_t)(r0)      * 2048 + kof]);
    bf16x8 va1 = *reinterpret_cast<const bf16x8*>(&Vtb[(size_t)(32 + r0) * 2048 + kof]);

    for (int kt = 0; kt <= qt; ++kt) {
        const int cur = kt & 1;
        const int k0 = kt * 64;

        *reinterpret_cast<bf16x8*>(&Ks[cur][(r0)      * AP + kof]) = ka0;
        *reinterpret_cast<bf16x8*>(&Ks[cur][(32 + r0) * AP + kof]) = ka1;
        *reinterpret_cast<bf16x8*>(&Vs[cur][(r0)      * AP + kof]) = va0;
        *reinterpret_cast<bf16x8*>(&Vs[cur][(32 + r0) * AP + kof]) = va1;
        asm volatile("s_waitcnt lgkmcnt(0)" ::: "memory");
        __builtin_amdgcn_s_barrier();
        __builtin_amdgcn_sched_barrier(0);

        if (kt < qt) {
            const int kn = k0 + 64;
            ka0 = *reinterpret_cast<const bf16x8*>(&Kb [(size_t)(kn + kperm)      * 1024 + kof]);
            ka1 = *reinterpret_cast<const bf16x8*>(&Kb [(size_t)(kn + 32 + kperm) * 1024 + kof]);
            va0 = *reinterpret_cast<const bf16x8*>(&Vtb[(size_t)(r0)      * 2048 + kn + kof]);
            va1 = *reinterpret_cast<const bf16x8*>(&Vtb[(size_t)(32 + r0) * 2048 + kn + kof]);
        }

        // swapped QK^T: sc[g][r] = S[key = k0+Key(16g+4lg+r)][q = q0w+lc]
        f32x4 sc[4];
#pragma unroll
        for (int g = 0; g < 4; ++g) sc[g] = (f32x4){0.f, 0.f, 0.f, 0.f};
        __builtin_amdgcn_s_setprio(1);
#pragma unroll
        for (int s = 0; s < 2; ++s)
#pragma unroll
            for (int g = 0; g < 4; ++g) {
                bf16x8 kf = *reinterpret_cast<const bf16x8*>(
                    &Ks[cur][(g * 16 + lc) * AP + s * 32 + lg * 8]);
                sc[g] = mfma16(kf, qf[s], sc[g]);
            }
        __builtin_amdgcn_s_setprio(0);

        if (kt == qt) {   // diagonal tile: strict causal + (0,0), permuted key ids
            const int qi = q0w + lc;
#pragma unroll
            for (int g = 0; g < 4; ++g)
#pragma unroll
                for (int r = 0; r < 4; ++r) {
                    const int ki = k0 + ((g & 2) << 4) + 8 * lg + 4 * (g & 1) + r;
                    const bool keep = (ki < qi) || (qi == 0 && ki == 0);
                    if (!keep) sc[g][r] = -1e30f;
                }
        }

        // fixed-shift softmax, fully lane-local
        float p[4][4];
#pragma unroll
        for (int g = 0; g < 4; ++g)
#pragma unroll
            for (int r = 0; r < 4; ++r) {
                p[g][r] = exp2f(sc[g][r] - SOFF2);
                lsum += p[g][r];
            }

        // PV: B-frag is lane-local by construction (permuted K staging)
#pragma unroll
        for (int s = 0; s < 2; ++s) {
            u32x4 fr;
            fr[0] = pk2(p[2 * s][0],     p[2 * s][1]);
            fr[1] = pk2(p[2 * s][2],     p[2 * s][3]);
            fr[2] = pk2(p[2 * s + 1][0], p[2 * s + 1][1]);
            fr[3] = pk2(p[2 * s + 1][2], p[2 * s + 1][3]);
            bf16x8 pb = __builtin_bit_cast(bf16x8, fr);
            __builtin_amdgcn_s_setprio(1);
#pragma unroll
            for (int di = 0; di < 4; ++di) {
                bf16x8 vf = *reinterpret_cast<const bf16x8*>(
                    &Vs[cur][(di * 16 + lc) * AP + s * 32 + lg * 8]);
                accT[di] = mfma16(vf, pb, accT[di]);
            }
            __builtin_amdgcn_s_setprio(0);
        }
    }

    // full row sum for q=lc: combine the 4 lg groups
    lsum += __shfl_xor(lsum, 16);
    lsum += __shfl_xor(lsum, 32);
    const float inv = 1.0f / lsum;

    const size_t orow = (size_t)(b * 2048 + q0w + lc) * 1024 + (size_t)h * 64 + lg * 4;
#pragma unroll
    for (int di = 0; di < 4; ++di) {
        unsigned lo  = pk2(accT[di][0] * inv, accT[di][1] * inv);
        unsigned hi2 = pk2(accT[di][2] * inv, accT[di][3] * inv);
        uint2 st; st.x = lo; st.y = hi2;
        *reinterpret_cast<uint2*>(&out[orow + di * 16]) = st;
    }
}

extern "C" void kernel_launch(void* const* d_in, const int* in_sizes, int n_in,
                              void* d_out, int out_size, void* d_ws, size_t ws_size,
                              hipStream_t stream)
{
    const float* q   = (const float*)d_in[0];
    const float* k   = (const float*)d_in[1];
    const float* v   = (const float*)d_in[2];
    const float* W_q = (const float*)d_in[3];
    const float* W_k = (const float*)d_in[4];
    const float* W_v = (const float*)d_in[5];
    const float* b_v = (const float*)d_in[6];
    const float* W_o = (const float*)d_in[7];
    const float* b_o = (const float*)d_in[8];

    char* w = (char*)d_ws;
    unsigned short* qkvb = (unsigned short*)w;                 // 3 x 4194304 bf16 (24 MiB)
    unsigned short* Wt   = (unsigned short*)(w + 25165824);    // 4 x 1048576 bf16 (8 MiB)
    unsigned short* ph   = (unsigned short*)(w + 33554432);    // qh,kh bf16 + vt slot (24 MiB)
    unsigned short* attn = (unsigned short*)(w + 58720256);    // 8 MiB
    unsigned short* vt   = ph + 2 * 4194304;                   // V^T written directly by proj z==2

    prep_k <<<dim3(10240, 1, 1), 256, 0, stream>>>(q, k, v, qkvb, W_q, W_k, W_v, W_o, Wt);
    gemm_proj_k<<<dim3(768, 1, 1), 256, 0, stream>>>(qkvb, Wt, ph, vt, b_v);
    attn_k <<<dim3(1024, 1, 1), 256, 0, stream>>>(ph, ph + 4194304, vt, attn);
    gemm_out_k<<<dim3(512, 1, 1), 256, 0, stream>>>(attn, Wt + 3 * 1048576, (float*)d_out, b_o);
}